// Round 2
// baseline (278.521 us; speedup 1.0000x reference)
//
#include <hip/hip_runtime.h>
#include <hip/hip_bf16.h>
#include <cstdint>
#include <cstddef>

#define DIM  128
#define NREL 8
#define SCB  4096   // elements per scan block (16 per thread)
#define CPB  32     // cols per fused block (64 KB LDS, 1024-thr blocks -> 2 blocks/CU = 32 waves)

typedef __attribute__((ext_vector_type(8))) short short8;
typedef __attribute__((ext_vector_type(4))) float f32x4;

static inline int cdiv(int a, int b){ return (a + b - 1) / b; }

__device__ inline unsigned short f2bf(float f){
    union { float f; uint32_t u; } v; v.f = f;
    uint32_t u = v.u;
    uint32_t r = (u + 0x7FFFu + ((u >> 16) & 1u)) >> 16;   // RNE
    return (unsigned short)r;
}
__device__ inline uint32_t pack2(float lo, float hi){
    return (uint32_t)f2bf(lo) | ((uint32_t)f2bf(hi) << 16);
}
__device__ inline float bf2f(uint32_t lo16){
    union { uint32_t u; float f; } v; v.u = lo16 << 16; return v.f;
}
__device__ inline float asf(int u){
    union { int i; float f; } v; v.i = u; return v.f;
}

// ---- fused prep: [0,nb4) xb convert | [nb4,nb4+eb) (col,type) histogram | [..,+128) wpk ----
// wpk B-frag for 16x16x32: lane l holds B[k = ks*32 + (l>>4)*8 + j][n = nt*16 + (l&15)]
__global__ __launch_bounds__(256) void k_prep(const float4* __restrict__ x, unsigned short* __restrict__ xb, int n4,
                                              const int* __restrict__ col, const int* __restrict__ et, int E,
                                              int* __restrict__ cnt8, int nb4, int eb,
                                              const float* __restrict__ W1, const float* __restrict__ W2,
                                              unsigned short* __restrict__ wpk){
    int blk = blockIdx.x;
    if (blk < nb4){
        int i = blk * 256 + threadIdx.x;
        if (i >= n4) return;
        float4 v = x[i];
        ushort4 o; o.x = f2bf(v.x); o.y = f2bf(v.y); o.z = f2bf(v.z); o.w = f2bf(v.w);
        *(ushort4*)(xb + (size_t)i * 4) = o;
    } else if (blk < nb4 + eb){
        int e = (blk - nb4) * 256 + threadIdx.x;
        if (e < E) atomicAdd(&cnt8[col[e] * NREL + et[e]], 1);
    } else {
        int b = (blk - nb4 - eb) * 4 + (threadIdx.x >> 6);   // ((slot*8+nt)*4+ks), 512 total
        int lane = threadIdx.x & 63;
        int ks = b & 3, nt = (b >> 2) & 7, slot = b >> 5;
        const float* Wsrc = (slot < 8) ? (W1 + (size_t)slot * DIM * DIM)
                                       : (W2 + (size_t)(slot - 8) * DIM * DIM);
        int k0 = ks * 32 + (lane >> 4) * 8;
        int n  = nt * 16 + (lane & 15);
        unsigned short o[8];
        #pragma unroll
        for (int j = 0; j < 8; ++j) o[j] = f2bf(Wsrc[(size_t)(k0 + j) * DIM + n]);
        unsigned short* dst = wpk + ((size_t)b * 64 + lane) * 8;
        #pragma unroll
        for (int j = 0; j < 8; ++j) dst[j] = o[j];
    }
}

// ---- hierarchical exclusive scan of cnt8 (M8 = N*8) -> start8[M8+1], pos8 ----
__global__ __launch_bounds__(256) void k_scan1(const int* __restrict__ cnt, int M, int* __restrict__ bsum){
    int t = threadIdx.x;
    int base = blockIdx.x * SCB + t * 16;
    int s = 0;
    #pragma unroll
    for (int k = 0; k < 16; ++k){
        int i = base + k;
        if (i < M) s += cnt[i];
    }
    #pragma unroll
    for (int o = 1; o < 64; o <<= 1) s += __shfl_xor(s, o);
    __shared__ int wsum[4];
    if ((t & 63) == 0) wsum[t >> 6] = s;
    __syncthreads();
    if (t == 0) bsum[blockIdx.x] = wsum[0] + wsum[1] + wsum[2] + wsum[3];
}

// scan3 absorbs the old scan2: every wave redundantly computes its block's bsum prefix
__global__ __launch_bounds__(256) void k_scan3(const int* __restrict__ cnt, int M,
                                               const int* __restrict__ bsum, int NBS,
                                               int* __restrict__ startArr, int* __restrict__ pos){
    int t = threadIdx.x;
    int base = blockIdx.x * SCB + t * 16;
    int vals[16];
    int s = 0;
    #pragma unroll
    for (int k = 0; k < 16; ++k){
        int i = base + k;
        vals[k] = (i < M) ? cnt[i] : 0;
        s += vals[k];
    }
    int lane = t & 63, w = t >> 6;

    // per-wave redundant prefix over bsum[0..blockIdx) (+ grand total for the last block)
    int bp = 0, tp = 0;
    for (int i = lane; i < NBS; i += 64){
        int bv = bsum[i];
        if (i < (int)blockIdx.x) bp += bv;
        tp += bv;
    }
    #pragma unroll
    for (int o = 1; o < 64; o <<= 1){ bp += __shfl_xor(bp, o); tp += __shfl_xor(tp, o); }

    int v = s;
    #pragma unroll
    for (int o = 1; o < 64; o <<= 1){
        int u = __shfl_up(v, o);
        if (lane >= o) v += u;
    }
    __shared__ int wsum[4];
    if (lane == 63) wsum[w] = v;
    __syncthreads();
    int excl = v - s + bp;
    for (int i = 0; i < w; ++i) excl += wsum[i];
    #pragma unroll
    for (int k = 0; k < 16; ++k){
        int i = base + k;
        if (i < M){ startArr[i] = excl; pos[i] = excl; excl += vals[k]; }
    }
    if (blockIdx.x == (unsigned)(gridDim.x - 1) && t == 0) startArr[M] = tp;
}

// ---- place edges sorted by (col,type); coef inline; meta {cl<<24 | row<<3 | type, coef} ----
// degree[c] = start8[(c+1)*8] - start8[c*8]  (k_colsum eliminated)
__global__ __launch_bounds__(256) void k_place(const int* __restrict__ row, const int* __restrict__ col,
                                               const int* __restrict__ et, const float* __restrict__ ew,
                                               const int* __restrict__ cs8,
                                               int E, int* __restrict__ pos8, int2* __restrict__ pkm){
    int e = blockIdx.x * 256 + threadIdx.x;
    if (e >= E) return;
    int r = row[e], c = col[e], t = et[e];
    int r8 = r << 3, c8 = c << 3;
    int dr = cs8[r8 + 8] - cs8[r8];
    int dc = cs8[c8 + 8] - cs8[c8];
    float a = dr > 0 ? rsqrtf((float)dr) : 0.f;
    float b = dc > 0 ? rsqrtf((float)dc) : 0.f;
    float cf = a * b * ew[e];
    int p = atomicAdd(&pos8[c8 + t], 1);
    union { float f; int i; } cv; cv.f = cf;
    pkm[p] = make_int2(((c & (CPB - 1)) << 24) | (r << 3) | t, cv.i);
}

// ---- fused aggregate + transform conv ----
// out[c] = bias + sum_t ( sum_{e: col=c, type=t} coef_e * x[row_e] ) @ W[t]
// 1024 threads = 16 waves; block owns 32 cols; 64 KB LDS -> 2 blocks/CU = 32 waves/CU.
// Phase 1: wave owns 2 cols, contiguous (col,type)-sorted edge range; metas 64-at-a-time
//   coalesced -> v_readlane; row gathers batched 8 deep (64-VGPR budget keeps them in
//   flight); run-segmented acc in 2 regs -> swizzled bf16 A-tile ds_write per run.
// Phase 2: wave (m = wid>>3, nt = wid&7) owns one 16x16 output tile, full K=1024.
//   No K-split -> no partial-reduce pass; B streamed from L2 (256 KB/block = 8 KB/col).
// Epilogue via LDS fp32 tile (reuse) -> coalesced stores.
template<int MODE>
__global__ __launch_bounds__(1024, 8) void k_fused(const unsigned short* __restrict__ xbin,
                                                   const unsigned short* __restrict__ wpk,
                                                   const int* __restrict__ cs8,
                                                   const int2* __restrict__ pkm,
                                                   const float* __restrict__ bias,
                                                   unsigned short* __restrict__ zb,
                                                   const unsigned short* __restrict__ xb2,
                                                   const unsigned short* __restrict__ z1b2,
                                                   float* __restrict__ outS,
                                                   float* __restrict__ outH,
                                                   int N, int wslot){
    __shared__ unsigned short s[CPB * 1024];    // 64 KB: bf16 A-tile, then fp32 out-tile
    int tid = threadIdx.x;
    int wid = tid >> 6, lane = tid & 63;
    int c0 = blockIdx.x * CPB;

    // zero the A-tile (4096 uint4 / 1024 threads)
    uint4 z4 = {0u, 0u, 0u, 0u};
    #pragma unroll
    for (int k = 0; k < 4; ++k) ((uint4*)s)[tid + 1024 * k] = z4;
    __syncthreads();

#define FLUSH() *(uint32_t*)((char*)s + flushByte) = pack2(a0, a1)
#define PROC(rt, cf, u) do{                                                       \
        int fk_ = (rt) & 0xFF000007;                                              \
        if (fk_ != fkPrev){                                                       \
            if (fkPrev >= 0) FLUSH();                                             \
            fkPrev = fk_;                                                         \
            int cl_ = ((unsigned)(rt)) >> 24; int t_ = (rt) & 7;                  \
            flushByte = cl_ * 2048 + (((t_ << 8) | (lane << 2)) ^ ((cl_ & 7) << 4)); \
            a0 = 0.f; a1 = 0.f;                                                   \
        }                                                                         \
        a0 = fmaf(cf, bf2f((u) & 0xFFFFu), a0);                                   \
        a1 = fmaf(cf, bf2f((u) >> 16),     a1); }while(0)
#define XROW(mx) ((const uint32_t*)(xbin + ((size_t)(((mx) >> 3) & 0x1FFFFF) << 7)))[lane]

    // ---- phase 1: 2 cols per wave, one contiguous edge range ----
    {
        int c = c0 + wid * 2;
        if (c < N){
            int cHi = c + 2; if (cHi > N) cHi = N;
            int e  = cs8[c * NREL];
            int eE = cs8[cHi * NREL];
            int fkPrev = -1;
            int flushByte = 0;
            float a0 = 0.f, a1 = 0.f;
            while (e < eE){
                int n = eE - e; if (n > 64) n = 64;
                int li = lane < n ? lane : n - 1;
                int2 mv = pkm[e + li];            // 64 metas, one coalesced load
                int j = 0;
                for (; j + 8 <= n; j += 8){
                    int rt[8]; float cf[8]; uint32_t u[8];
                    #pragma unroll
                    for (int k = 0; k < 8; ++k){
                        rt[k] = __builtin_amdgcn_readlane(mv.x, j + k);
                        cf[k] = asf(__builtin_amdgcn_readlane(mv.y, j + k));
                    }
                    #pragma unroll
                    for (int k = 0; k < 8; ++k) u[k] = XROW(rt[k]);
                    #pragma unroll
                    for (int k = 0; k < 8; ++k) PROC(rt[k], cf[k], u[k]);
                }
                for (; j < n; ++j){
                    int rt = __builtin_amdgcn_readlane(mv.x, j);
                    float cf = asf(__builtin_amdgcn_readlane(mv.y, j));
                    uint32_t u = XROW(rt);
                    PROC(rt, cf, u);
                }
                e += n;
            }
            if (fkPrev >= 0) FLUSH();
        }
    }
#undef PROC
#undef FLUSH
#undef XROW
    __syncthreads();

    // ---- phase 2: wave (m = wid>>3, nt = wid&7): one 16x16 tile, K=1024 ----
    int m = wid >> 3, nt = wid & 7;
    f32x4 acc = (f32x4){0,0,0,0};

    int al = lane & 15, ak2 = (lane >> 4) * 16;
    int swz = (al & 7) << 4;
    const char* rowA = (const char*)s + (m * 16 + al) * 2048;

    const short8* bbase = (const short8*)wpk + (size_t)wslot * 2048 + lane;

    #pragma unroll 4
    for (int ksg = 0; ksg < 32; ++ksg){
        int off = (ksg * 64 + ak2) ^ swz;
        short8 A = *(const short8*)(rowA + off);
        int t = ksg >> 2, ksl = ksg & 3;
        short8 B = (bbase + (size_t)t * 2048)[(nt * 4 + ksl) * 64];
        acc = __builtin_amdgcn_mfma_f32_16x16x32_bf16(A, B, acc, 0, 0, 0);
    }
    __syncthreads();   // all A-reads done; reuse s as fp32 out-tile

    // ---- stage C tile to LDS (bias + relu applied here) ----
    float* ot = (float*)s;   // [CPB][128]
    int crb = (lane >> 4) * 4, dcl = lane & 15;
    {
        int d = nt * 16 + dcl;
        float bv = bias[d];
        #pragma unroll
        for (int r = 0; r < 4; ++r){
            int mrow = m * 16 + crb + r;
            float v = acc[r] + bv;
            if (MODE == 0) v = fmaxf(v, 0.f);
            ot[mrow * DIM + d] = v;
        }
    }
    __syncthreads();

    // ---- coalesced output ----
    if (MODE == 0){
        if (tid < 512){
            int rowi = tid >> 4, seg = tid & 15;
            int c = c0 + rowi;
            if (c < N){
                const float* src = ot + rowi * DIM + seg * 8;
                uint4 vv;
                vv.x = pack2(src[0], src[1]);
                vv.y = pack2(src[2], src[3]);
                vv.z = pack2(src[4], src[5]);
                vv.w = pack2(src[6], src[7]);
                *(uint4*)(zb + ((size_t)c << 7) + seg * 8) = vv;
            }
        }
    } else {
        int rowi = tid >> 5, q = tid & 31;
        int c = c0 + rowi;
        if (c < N){
            int d0 = q * 4;
            size_t o = ((size_t)c << 7) + d0;
            ushort4 xv4 = *(const ushort4*)(xb2 + o);
            ushort4 zv4 = *(const ushort4*)(z1b2 + o);
            const float* src = ot + rowi * DIM + d0;
            f32x4 S, H;
            {
                float xv = bf2f(xv4.x), z1 = bf2f(zv4.x), v = src[0];
                S.x = (xv + z1 + v) * 0.25f; H.x = (z1 + v) * (1.0f / 3.0f);
            }
            {
                float xv = bf2f(xv4.y), z1 = bf2f(zv4.y), v = src[1];
                S.y = (xv + z1 + v) * 0.25f; H.y = (z1 + v) * (1.0f / 3.0f);
            }
            {
                float xv = bf2f(xv4.z), z1 = bf2f(zv4.z), v = src[2];
                S.z = (xv + z1 + v) * 0.25f; H.z = (z1 + v) * (1.0f / 3.0f);
            }
            {
                float xv = bf2f(xv4.w), z1 = bf2f(zv4.w), v = src[3];
                S.w = (xv + z1 + v) * 0.25f; H.w = (z1 + v) * (1.0f / 3.0f);
            }
            __builtin_nontemporal_store(S, (f32x4*)(outS + o));
            __builtin_nontemporal_store(H, (f32x4*)(outH + o));
        }
    }
}

extern "C" void kernel_launch(void* const* d_in, const int* in_sizes, int n_in,
                              void* d_out, int out_size, void* d_ws, size_t ws_size,
                              hipStream_t stream) {
    const float* x  = (const float*)d_in[0];
    const int*   ei = (const int*)d_in[1];
    const int*   et = (const int*)d_in[2];
    const float* ew = (const float*)d_in[3];
    const float* W1 = (const float*)d_in[4];
    const float* b1 = (const float*)d_in[5];
    const float* W2 = (const float*)d_in[6];
    const float* b2 = (const float*)d_in[7];

    int E = in_sizes[2];
    int N = in_sizes[0] / DIM;
    const int* row = ei;
    const int* col = ei + E;

    float* out = (float*)d_out;
    int ND  = N * DIM;
    int ND4 = ND / 4;
    float* zS = out;        // slot 0: z_star
    float* zH = out + ND;   // slot 1: z_sharp

    int M8   = N * NREL;
    int NBS8 = cdiv(M8, SCB);

    // ---- workspace carve (~70 MB) ----
    char* wsb = (char*)d_ws;
    size_t off = 0;
    auto take = [&](size_t bytes) -> char* {
        char* p = wsb + off;
        off = (off + bytes + 255) & ~(size_t)255;
        return p;
    };
    int*            cnt8     = (int*)           take((size_t)M8 * 4);
    int*            start8   = (int*)           take(((size_t)M8 + 1) * 4);
    int*            pos8     = (int*)           take((size_t)M8 * 4);
    int*            bsum     = (int*)           take(((size_t)NBS8 + 1) * 4);
    int2*           pkm      = (int2*)          take((size_t)E * 8);
    unsigned short* wpk      = (unsigned short*)take((size_t)16 * 2048 * 8 * 2);   // 512 KB
    unsigned short* xb       = (unsigned short*)take((size_t)ND * 2);
    unsigned short* z1b      = (unsigned short*)take((size_t)ND * 2);
    (void)n_in; (void)out_size; (void)ws_size;

    hipMemsetAsync(cnt8, 0, (size_t)M8 * 4, stream);

    int eb  = cdiv(E, 256);
    int nb4 = cdiv(ND4, 256);
    k_prep  <<<nb4 + eb + 128, 256, 0, stream>>>((const float4*)x, xb, ND4, col, et, E, cnt8, nb4, eb, W1, W2, wpk);
    k_scan1 <<<NBS8, 256, 0, stream>>>(cnt8, M8, bsum);
    k_scan3 <<<NBS8, 256, 0, stream>>>(cnt8, M8, bsum, NBS8, start8, pos8);
    k_place <<<eb, 256, 0, stream>>>(row, col, et, ew, start8, E, pos8, pkm);

    int fb = cdiv(N, CPB);
    // conv1: z1b = bf16(relu(agg(x) @ W1 + b1))
    k_fused<0><<<fb, 1024, 0, stream>>>(xb, wpk, start8, pkm, b1, z1b, nullptr, nullptr, nullptr, nullptr, N, 0);
    // conv2: fused z_star/z_sharp from xb, z1b, agg(z1b) @ W2 + b2
    k_fused<1><<<fb, 1024, 0, stream>>>(z1b, wpk, start8, pkm, b2, nullptr, xb, z1b, zS, zH, N, 8);
}

// Round 3
// 248.915 us; speedup vs baseline: 1.1189x; 1.1189x over previous
//
#include <hip/hip_runtime.h>
#include <hip/hip_bf16.h>
#include <cstdint>
#include <cstddef>

#define DIM  128
#define NREL 8
#define SCB  4096   // elements per scan block (16 per thread)
#define CPB  16     // cols per fused block (32 KB LDS, 512-thr blocks -> 4 blocks/CU = 32 waves)

typedef __attribute__((ext_vector_type(8))) short short8;
typedef __attribute__((ext_vector_type(4))) float f32x4;

static inline int cdiv(int a, int b){ return (a + b - 1) / b; }

__device__ inline unsigned short f2bf(float f){
    union { float f; uint32_t u; } v; v.f = f;
    uint32_t u = v.u;
    uint32_t r = (u + 0x7FFFu + ((u >> 16) & 1u)) >> 16;   // RNE
    return (unsigned short)r;
}
__device__ inline uint32_t pack2(float lo, float hi){
    return (uint32_t)f2bf(lo) | ((uint32_t)f2bf(hi) << 16);
}
__device__ inline float bf2f(uint32_t lo16){
    union { uint32_t u; float f; } v; v.u = lo16 << 16; return v.f;
}
__device__ inline float asf(int u){
    union { int i; float f; } v; v.i = u; return v.f;
}

// ---- fused prep: [0,nb4) xb convert | [nb4,nb4+eb) (col,type) histogram | [..,+128) wpk ----
// wpk B-frag for 16x16x32: lane l holds B[k = ks*32 + (l>>4)*8 + j][n = nt*16 + (l&15)]
__global__ __launch_bounds__(256) void k_prep(const float4* __restrict__ x, unsigned short* __restrict__ xb, int n4,
                                              const int* __restrict__ col, const int* __restrict__ et, int E,
                                              int* __restrict__ cnt8, int nb4, int eb,
                                              const float* __restrict__ W1, const float* __restrict__ W2,
                                              unsigned short* __restrict__ wpk){
    int blk = blockIdx.x;
    if (blk < nb4){
        int i = blk * 256 + threadIdx.x;
        if (i >= n4) return;
        float4 v = x[i];
        ushort4 o; o.x = f2bf(v.x); o.y = f2bf(v.y); o.z = f2bf(v.z); o.w = f2bf(v.w);
        *(ushort4*)(xb + (size_t)i * 4) = o;
    } else if (blk < nb4 + eb){
        int e = (blk - nb4) * 256 + threadIdx.x;
        if (e < E) atomicAdd(&cnt8[col[e] * NREL + et[e]], 1);
    } else {
        int b = (blk - nb4 - eb) * 4 + (threadIdx.x >> 6);   // ((slot*8+nt)*4+ks), 512 total
        int lane = threadIdx.x & 63;
        int ks = b & 3, nt = (b >> 2) & 7, slot = b >> 5;
        const float* Wsrc = (slot < 8) ? (W1 + (size_t)slot * DIM * DIM)
                                       : (W2 + (size_t)(slot - 8) * DIM * DIM);
        int k0 = ks * 32 + (lane >> 4) * 8;
        int n  = nt * 16 + (lane & 15);
        unsigned short o[8];
        #pragma unroll
        for (int j = 0; j < 8; ++j) o[j] = f2bf(Wsrc[(size_t)(k0 + j) * DIM + n]);
        unsigned short* dst = wpk + ((size_t)b * 64 + lane) * 8;
        #pragma unroll
        for (int j = 0; j < 8; ++j) dst[j] = o[j];
    }
}

// ---- hierarchical exclusive scan of cnt8 (M8 = N*8) -> start8[M8+1], pos8 ----
__global__ __launch_bounds__(256) void k_scan1(const int* __restrict__ cnt, int M, int* __restrict__ bsum){
    int t = threadIdx.x;
    int base = blockIdx.x * SCB + t * 16;
    int s = 0;
    #pragma unroll
    for (int k = 0; k < 16; ++k){
        int i = base + k;
        if (i < M) s += cnt[i];
    }
    #pragma unroll
    for (int o = 1; o < 64; o <<= 1) s += __shfl_xor(s, o);
    __shared__ int wsum[4];
    if ((t & 63) == 0) wsum[t >> 6] = s;
    __syncthreads();
    if (t == 0) bsum[blockIdx.x] = wsum[0] + wsum[1] + wsum[2] + wsum[3];
}

// scan3 absorbs the old scan2: every wave redundantly computes its block's bsum prefix
__global__ __launch_bounds__(256) void k_scan3(const int* __restrict__ cnt, int M,
                                               const int* __restrict__ bsum, int NBS,
                                               int* __restrict__ startArr, int* __restrict__ pos){
    int t = threadIdx.x;
    int base = blockIdx.x * SCB + t * 16;
    int vals[16];
    int s = 0;
    #pragma unroll
    for (int k = 0; k < 16; ++k){
        int i = base + k;
        vals[k] = (i < M) ? cnt[i] : 0;
        s += vals[k];
    }
    int lane = t & 63, w = t >> 6;

    // per-wave redundant prefix over bsum[0..blockIdx) (+ grand total for the last block)
    int bp = 0, tp = 0;
    for (int i = lane; i < NBS; i += 64){
        int bv = bsum[i];
        if (i < (int)blockIdx.x) bp += bv;
        tp += bv;
    }
    #pragma unroll
    for (int o = 1; o < 64; o <<= 1){ bp += __shfl_xor(bp, o); tp += __shfl_xor(tp, o); }

    int v = s;
    #pragma unroll
    for (int o = 1; o < 64; o <<= 1){
        int u = __shfl_up(v, o);
        if (lane >= o) v += u;
    }
    __shared__ int wsum[4];
    if (lane == 63) wsum[w] = v;
    __syncthreads();
    int excl = v - s + bp;
    for (int i = 0; i < w; ++i) excl += wsum[i];
    #pragma unroll
    for (int k = 0; k < 16; ++k){
        int i = base + k;
        if (i < M){ startArr[i] = excl; pos[i] = excl; excl += vals[k]; }
    }
    if (blockIdx.x == (unsigned)(gridDim.x - 1) && t == 0) startArr[M] = tp;
}

// ---- place edges sorted by (col,type); coef inline; meta {cl<<24 | row<<3 | type, coef} ----
// degree[c] = start8[(c+1)*8] - start8[c*8]  (k_colsum eliminated)
__global__ __launch_bounds__(256) void k_place(const int* __restrict__ row, const int* __restrict__ col,
                                               const int* __restrict__ et, const float* __restrict__ ew,
                                               const int* __restrict__ cs8,
                                               int E, int* __restrict__ pos8, int2* __restrict__ pkm){
    int e = blockIdx.x * 256 + threadIdx.x;
    if (e >= E) return;
    int r = row[e], c = col[e], t = et[e];
    int r8 = r << 3, c8 = c << 3;
    int dr = cs8[r8 + 8] - cs8[r8];
    int dc = cs8[c8 + 8] - cs8[c8];
    float a = dr > 0 ? rsqrtf((float)dr) : 0.f;
    float b = dc > 0 ? rsqrtf((float)dc) : 0.f;
    float cf = a * b * ew[e];
    int p = atomicAdd(&pos8[c8 + t], 1);
    union { float f; int i; } cv; cv.f = cf;
    pkm[p] = make_int2(((c & (CPB - 1)) << 24) | (r << 3) | t, cv.i);
}

// ---- fused aggregate + transform conv ----
// out[c] = bias + sum_t ( sum_{e: col=c, type=t} coef_e * x[row_e] ) @ W[t]
// 512 threads = 8 waves; block owns 16 cols; 32 KB LDS -> 4 blocks/CU = 32 waves/CU.
// Phase 1: wave owns 2 cols, contiguous (col,type)-sorted edge range; metas 64-at-a-time
//   coalesced -> v_readlane; row gathers in ONE masked 16-deep batch (pad slots clamp
//   to edge n-1 with coef=0: duplicate rt -> no spurious flush, fma(0,.) -> no-op), so a
//   typical wave (n~13) pays a single gather-latency exposure, not ~6 serial ones.
// Phase 2: wave nt=wid owns one 16x16 N-slice, full K=1024; B streamed from L2.
// Epilogue via LDS fp32 tile (reuse) -> coalesced stores.
template<int MODE>
__global__ __launch_bounds__(512, 8) void k_fused(const unsigned short* __restrict__ xbin,
                                                  const unsigned short* __restrict__ wpk,
                                                  const int* __restrict__ cs8,
                                                  const int2* __restrict__ pkm,
                                                  const float* __restrict__ bias,
                                                  unsigned short* __restrict__ zb,
                                                  const unsigned short* __restrict__ xb2,
                                                  const unsigned short* __restrict__ z1b2,
                                                  float* __restrict__ outS,
                                                  float* __restrict__ outH,
                                                  int N, int wslot){
    __shared__ unsigned short s[CPB * 1024];    // 32 KB: bf16 A-tile, then fp32 out-tile
    int tid = threadIdx.x;
    int wid = tid >> 6, lane = tid & 63;
    int c0 = blockIdx.x * CPB;

    // zero the A-tile (2048 uint4 / 512 threads)
    uint4 z4 = {0u, 0u, 0u, 0u};
    #pragma unroll
    for (int k = 0; k < 4; ++k) ((uint4*)s)[tid + 512 * k] = z4;
    __syncthreads();

#define FLUSH() *(uint32_t*)((char*)s + flushByte) = pack2(a0, a1)
#define PROC(rt, cf, u) do{                                                       \
        int fk_ = (rt) & 0xFF000007;                                              \
        if (fk_ != fkPrev){                                                       \
            if (fkPrev >= 0) FLUSH();                                             \
            fkPrev = fk_;                                                         \
            int cl_ = ((unsigned)(rt)) >> 24; int t_ = (rt) & 7;                  \
            flushByte = cl_ * 2048 + (((t_ << 8) | (lane << 2)) ^ ((cl_ & 7) << 4)); \
            a0 = 0.f; a1 = 0.f;                                                   \
        }                                                                         \
        a0 = fmaf(cf, bf2f((u) & 0xFFFFu), a0);                                   \
        a1 = fmaf(cf, bf2f((u) >> 16),     a1); }while(0)
#define XROW(mx) ((const uint32_t*)(xbin + ((size_t)(((mx) >> 3) & 0x1FFFFF) << 7)))[lane]

    // ---- phase 1: 2 cols per wave, one contiguous edge range ----
    {
        int c = c0 + wid * 2;
        if (c < N){
            int cHi = c + 2; if (cHi > N) cHi = N;
            int e  = cs8[c * NREL];
            int eE = cs8[cHi * NREL];
            int fkPrev = -1;
            int flushByte = 0;
            float a0 = 0.f, a1 = 0.f;
            while (e < eE){
                int n = eE - e; if (n > 64) n = 64;
                int li = lane < n ? lane : n - 1;
                int2 mv = pkm[e + li];            // 64 metas, one coalesced load
                for (int j = 0; j < n; j += 16){
                    int rt[16]; float cf[16]; uint32_t u[16];
                    #pragma unroll
                    for (int k = 0; k < 16; ++k){
                        int idx = j + k;
                        int live = idx < n;
                        idx = live ? idx : n - 1;           // clamp: duplicate last edge
                        rt[k] = __builtin_amdgcn_readlane(mv.x, idx);
                        float cv = asf(__builtin_amdgcn_readlane(mv.y, idx));
                        cf[k] = live ? cv : 0.f;            // masked slots contribute 0
                    }
                    #pragma unroll
                    for (int k = 0; k < 16; ++k) u[k] = XROW(rt[k]);
                    #pragma unroll
                    for (int k = 0; k < 16; ++k) PROC(rt[k], cf[k], u[k]);
                }
                e += n;
            }
            if (fkPrev >= 0) FLUSH();
        }
    }
#undef PROC
#undef FLUSH
#undef XROW
    __syncthreads();

    // ---- phase 2: wave nt=wid: one 16(rows) x 16(dims) tile, K=1024 ----
    int nt = wid;
    f32x4 acc = (f32x4){0,0,0,0};

    int al = lane & 15, ak2 = (lane >> 4) * 16;
    int swz = (al & 7) << 4;
    const char* rowA = (const char*)s + al * 2048;

    const short8* bbase = (const short8*)wpk + (size_t)wslot * 2048 + lane;

    #pragma unroll 4
    for (int ksg = 0; ksg < 32; ++ksg){
        int off = (ksg * 64 + ak2) ^ swz;
        short8 A = *(const short8*)(rowA + off);
        int t = ksg >> 2, ksl = ksg & 3;
        short8 B = (bbase + (size_t)t * 2048)[(nt * 4 + ksl) * 64];
        acc = __builtin_amdgcn_mfma_f32_16x16x32_bf16(A, B, acc, 0, 0, 0);
    }
    __syncthreads();   // all A-reads done; reuse s as fp32 out-tile

    // ---- stage C tile to LDS (bias + relu applied here) ----
    float* ot = (float*)s;   // [CPB][128]
    int crb = (lane >> 4) * 4, dcl = lane & 15;
    {
        int d = nt * 16 + dcl;
        float bv = bias[d];
        #pragma unroll
        for (int r = 0; r < 4; ++r){
            int mrow = crb + r;
            float v = acc[r] + bv;
            if (MODE == 0) v = fmaxf(v, 0.f);
            ot[mrow * DIM + d] = v;
        }
    }
    __syncthreads();

    // ---- coalesced output ----
    if (MODE == 0){
        if (tid < 256){
            int rowi = tid >> 4, seg = tid & 15;
            int c = c0 + rowi;
            if (c < N){
                const float* src = ot + rowi * DIM + seg * 8;
                uint4 vv;
                vv.x = pack2(src[0], src[1]);
                vv.y = pack2(src[2], src[3]);
                vv.z = pack2(src[4], src[5]);
                vv.w = pack2(src[6], src[7]);
                *(uint4*)(zb + ((size_t)c << 7) + seg * 8) = vv;
            }
        }
    } else {
        int rowi = tid >> 5, q = tid & 31;
        int c = c0 + rowi;
        if (c < N){
            int d0 = q * 4;
            size_t o = ((size_t)c << 7) + d0;
            ushort4 xv4 = *(const ushort4*)(xb2 + o);
            ushort4 zv4 = *(const ushort4*)(z1b2 + o);
            const float* src = ot + rowi * DIM + d0;
            f32x4 S, H;
            {
                float xv = bf2f(xv4.x), z1 = bf2f(zv4.x), v = src[0];
                S.x = (xv + z1 + v) * 0.25f; H.x = (z1 + v) * (1.0f / 3.0f);
            }
            {
                float xv = bf2f(xv4.y), z1 = bf2f(zv4.y), v = src[1];
                S.y = (xv + z1 + v) * 0.25f; H.y = (z1 + v) * (1.0f / 3.0f);
            }
            {
                float xv = bf2f(xv4.z), z1 = bf2f(zv4.z), v = src[2];
                S.z = (xv + z1 + v) * 0.25f; H.z = (z1 + v) * (1.0f / 3.0f);
            }
            {
                float xv = bf2f(xv4.w), z1 = bf2f(zv4.w), v = src[3];
                S.w = (xv + z1 + v) * 0.25f; H.w = (z1 + v) * (1.0f / 3.0f);
            }
            __builtin_nontemporal_store(S, (f32x4*)(outS + o));
            __builtin_nontemporal_store(H, (f32x4*)(outH + o));
        }
    }
}

extern "C" void kernel_launch(void* const* d_in, const int* in_sizes, int n_in,
                              void* d_out, int out_size, void* d_ws, size_t ws_size,
                              hipStream_t stream) {
    const float* x  = (const float*)d_in[0];
    const int*   ei = (const int*)d_in[1];
    const int*   et = (const int*)d_in[2];
    const float* ew = (const float*)d_in[3];
    const float* W1 = (const float*)d_in[4];
    const float* b1 = (const float*)d_in[5];
    const float* W2 = (const float*)d_in[6];
    const float* b2 = (const float*)d_in[7];

    int E = in_sizes[2];
    int N = in_sizes[0] / DIM;
    const int* row = ei;
    const int* col = ei + E;

    float* out = (float*)d_out;
    int ND  = N * DIM;
    int ND4 = ND / 4;
    float* zS = out;        // slot 0: z_star
    float* zH = out + ND;   // slot 1: z_sharp

    int M8   = N * NREL;
    int NBS8 = cdiv(M8, SCB);

    // ---- workspace carve (~70 MB) ----
    char* wsb = (char*)d_ws;
    size_t off = 0;
    auto take = [&](size_t bytes) -> char* {
        char* p = wsb + off;
        off = (off + bytes + 255) & ~(size_t)255;
        return p;
    };
    int*            cnt8     = (int*)           take((size_t)M8 * 4);
    int*            start8   = (int*)           take(((size_t)M8 + 1) * 4);
    int*            pos8     = (int*)           take((size_t)M8 * 4);
    int*            bsum     = (int*)           take(((size_t)NBS8 + 1) * 4);
    int2*           pkm      = (int2*)          take((size_t)E * 8);
    unsigned short* wpk      = (unsigned short*)take((size_t)16 * 2048 * 8 * 2);   // 512 KB
    unsigned short* xb       = (unsigned short*)take((size_t)ND * 2);
    unsigned short* z1b      = (unsigned short*)take((size_t)ND * 2);
    (void)n_in; (void)out_size; (void)ws_size;

    hipMemsetAsync(cnt8, 0, (size_t)M8 * 4, stream);

    int eb  = cdiv(E, 256);
    int nb4 = cdiv(ND4, 256);
    k_prep  <<<nb4 + eb + 128, 256, 0, stream>>>((const float4*)x, xb, ND4, col, et, E, cnt8, nb4, eb, W1, W2, wpk);
    k_scan1 <<<NBS8, 256, 0, stream>>>(cnt8, M8, bsum);
    k_scan3 <<<NBS8, 256, 0, stream>>>(cnt8, M8, bsum, NBS8, start8, pos8);
    k_place <<<eb, 256, 0, stream>>>(row, col, et, ew, start8, E, pos8, pkm);

    int fb = cdiv(N, CPB);
    // conv1: z1b = bf16(relu(agg(x) @ W1 + b1))
    k_fused<0><<<fb, 512, 0, stream>>>(xb, wpk, start8, pkm, b1, z1b, nullptr, nullptr, nullptr, nullptr, N, 0);
    // conv2: fused z_star/z_sharp from xb, z1b, agg(z1b) @ W2 + b2
    k_fused<1><<<fb, 512, 0, stream>>>(z1b, wpk, start8, pkm, b2, nullptr, xb, z1b, zS, zH, N, 8);
}

// Round 4
// 245.537 us; speedup vs baseline: 1.1343x; 1.0138x over previous
//
#include <hip/hip_runtime.h>
#include <hip/hip_bf16.h>
#include <cstdint>
#include <cstddef>

#define DIM  128
#define NREL 8
#define SCB  4096   // elements per scan block (16 per thread)
#define CPB  16     // cols per fused block (32 KB LDS, 512-thr blocks -> 4 blocks/CU = 32 waves)

typedef __attribute__((ext_vector_type(8))) short short8;
typedef __attribute__((ext_vector_type(4))) float f32x4;

static inline int cdiv(int a, int b){ return (a + b - 1) / b; }

// single-instruction packed fp32x2 -> bf16x2 (RNE), replaces manual bit-twiddle
__device__ inline uint32_t packrn(float lo, float hi){
    __hip_bfloat162 h = __float22bfloat162_rn(make_float2(lo, hi));
    union { __hip_bfloat162 h; uint32_t u; } v; v.h = h; return v.u;
}
__device__ inline float bf2f(uint32_t lo16){
    union { uint32_t u; float f; } v; v.u = lo16 << 16; return v.f;
}
__device__ inline float asf(int u){
    union { int i; float f; } v; v.i = u; return v.f;
}

// ---- fused prep: [0,nb4) xb convert | [nb4,nb4+eb) (col,type) histogram | [..,+128) wpk ----
// wpk B-frag for 16x16x32: lane l holds B[k = ks*32 + (l>>4)*8 + j][n = nt*16 + (l&15)]
__global__ __launch_bounds__(256) void k_prep(const float4* __restrict__ x, unsigned short* __restrict__ xb, int n4,
                                              const int* __restrict__ col, const int* __restrict__ et, int E,
                                              int* __restrict__ cnt8, int nb4, int eb,
                                              const float* __restrict__ W1, const float* __restrict__ W2,
                                              unsigned short* __restrict__ wpk){
    int blk = blockIdx.x;
    if (blk < nb4){
        int i = blk * 256 + threadIdx.x;
        if (i >= n4) return;
        float4 v = x[i];
        uint2 o; o.x = packrn(v.x, v.y); o.y = packrn(v.z, v.w);
        *(uint2*)(xb + (size_t)i * 4) = o;
    } else if (blk < nb4 + eb){
        int e = (blk - nb4) * 256 + threadIdx.x;
        if (e < E) atomicAdd(&cnt8[col[e] * NREL + et[e]], 1);
    } else {
        int b = (blk - nb4 - eb) * 4 + (threadIdx.x >> 6);   // ((slot*8+nt)*4+ks), 512 total
        int lane = threadIdx.x & 63;
        int ks = b & 3, nt = (b >> 2) & 7, slot = b >> 5;
        const float* Wsrc = (slot < 8) ? (W1 + (size_t)slot * DIM * DIM)
                                       : (W2 + (size_t)(slot - 8) * DIM * DIM);
        int k0 = ks * 32 + (lane >> 4) * 8;
        int n  = nt * 16 + (lane & 15);
        uint4 ow;
        ow.x = packrn(Wsrc[(size_t)(k0 + 0) * DIM + n], Wsrc[(size_t)(k0 + 1) * DIM + n]);
        ow.y = packrn(Wsrc[(size_t)(k0 + 2) * DIM + n], Wsrc[(size_t)(k0 + 3) * DIM + n]);
        ow.z = packrn(Wsrc[(size_t)(k0 + 4) * DIM + n], Wsrc[(size_t)(k0 + 5) * DIM + n]);
        ow.w = packrn(Wsrc[(size_t)(k0 + 6) * DIM + n], Wsrc[(size_t)(k0 + 7) * DIM + n]);
        *(uint4*)(wpk + ((size_t)b * 64 + lane) * 8) = ow;
    }
}

// ---- hierarchical exclusive scan of cnt8 (M8 = N*8) -> start8[M8+1], pos8 ----
__global__ __launch_bounds__(256) void k_scan1(const int* __restrict__ cnt, int M, int* __restrict__ bsum){
    int t = threadIdx.x;
    int base = blockIdx.x * SCB + t * 16;
    int s = 0;
    #pragma unroll
    for (int k = 0; k < 16; ++k){
        int i = base + k;
        if (i < M) s += cnt[i];
    }
    #pragma unroll
    for (int o = 1; o < 64; o <<= 1) s += __shfl_xor(s, o);
    __shared__ int wsum[4];
    if ((t & 63) == 0) wsum[t >> 6] = s;
    __syncthreads();
    if (t == 0) bsum[blockIdx.x] = wsum[0] + wsum[1] + wsum[2] + wsum[3];
}

// scan3 absorbs the old scan2: every wave redundantly computes its block's bsum prefix
__global__ __launch_bounds__(256) void k_scan3(const int* __restrict__ cnt, int M,
                                               const int* __restrict__ bsum, int NBS,
                                               int* __restrict__ startArr, int* __restrict__ pos){
    int t = threadIdx.x;
    int base = blockIdx.x * SCB + t * 16;
    int vals[16];
    int s = 0;
    #pragma unroll
    for (int k = 0; k < 16; ++k){
        int i = base + k;
        vals[k] = (i < M) ? cnt[i] : 0;
        s += vals[k];
    }
    int lane = t & 63, w = t >> 6;

    // per-wave redundant prefix over bsum[0..blockIdx) (+ grand total for the last block)
    int bp = 0, tp = 0;
    for (int i = lane; i < NBS; i += 64){
        int bv = bsum[i];
        if (i < (int)blockIdx.x) bp += bv;
        tp += bv;
    }
    #pragma unroll
    for (int o = 1; o < 64; o <<= 1){ bp += __shfl_xor(bp, o); tp += __shfl_xor(tp, o); }

    int v = s;
    #pragma unroll
    for (int o = 1; o < 64; o <<= 1){
        int u = __shfl_up(v, o);
        if (lane >= o) v += u;
    }
    __shared__ int wsum[4];
    if (lane == 63) wsum[w] = v;
    __syncthreads();
    int excl = v - s + bp;
    for (int i = 0; i < w; ++i) excl += wsum[i];
    #pragma unroll
    for (int k = 0; k < 16; ++k){
        int i = base + k;
        if (i < M){ startArr[i] = excl; pos[i] = excl; excl += vals[k]; }
    }
    if (blockIdx.x == (unsigned)(gridDim.x - 1) && t == 0) startArr[M] = tp;
}

// ---- place edges sorted by (col,type); coef inline ----
// meta x = cl<<28 | type<<25 | row   (row < 2^17; run key = top 7 bits)
// degree[c] = start8[(c+1)*8] - start8[c*8]  (k_colsum eliminated)
__global__ __launch_bounds__(256) void k_place(const int* __restrict__ row, const int* __restrict__ col,
                                               const int* __restrict__ et, const float* __restrict__ ew,
                                               const int* __restrict__ cs8,
                                               int E, int* __restrict__ pos8, int2* __restrict__ pkm){
    int e = blockIdx.x * 256 + threadIdx.x;
    if (e >= E) return;
    int r = row[e], c = col[e], t = et[e];
    int r8 = r << 3, c8 = c << 3;
    int dr = cs8[r8 + 8] - cs8[r8];
    int dc = cs8[c8 + 8] - cs8[c8];
    float a = dr > 0 ? rsqrtf((float)dr) : 0.f;
    float b = dc > 0 ? rsqrtf((float)dc) : 0.f;
    float cf = a * b * ew[e];
    int p = atomicAdd(&pos8[c8 + t], 1);
    union { float f; int i; } cv; cv.f = cf;
    pkm[p] = make_int2(((c & (CPB - 1)) << 28) | (t << 25) | r, cv.i);
}

// ---- fused aggregate + transform conv ----
// out[c] = bias + sum_t ( sum_{e: col=c, type=t} coef_e * x[row_e] ) @ W[t]
// 512 threads = 8 waves; block owns 16 cols; 32 KB LDS -> 4 blocks/CU = 32 waves/CU.
// Phase 1: wave owns 2 cols, contiguous (col,type)-sorted edge range; metas 64-at-a-time
//   coalesced -> v_readlane (uniform -> SGPR); full 16-deep unmasked batches + one masked
//   tail batch; sched_barrier keeps the gather burst ahead of the serial PROC chain.
//   Run key = meta>>25 (7 bits); flushByte derived in 4 ops; flush packs via cvt_pk.
// Phase 2: wave nt=wid owns one 16x16 N-slice, full K=1024; B streamed from L2.
// Epilogue via LDS fp32 tile (reuse) -> coalesced stores.
template<int MODE>
__global__ __launch_bounds__(512, 8) void k_fused(const unsigned short* __restrict__ xbin,
                                                  const unsigned short* __restrict__ wpk,
                                                  const int* __restrict__ cs8,
                                                  const int2* __restrict__ pkm,
                                                  const float* __restrict__ bias,
                                                  unsigned short* __restrict__ zb,
                                                  const unsigned short* __restrict__ xb2,
                                                  const unsigned short* __restrict__ z1b2,
                                                  float* __restrict__ outS,
                                                  float* __restrict__ outH,
                                                  int N, int wslot){
    __shared__ unsigned short s[CPB * 1024];    // 32 KB: bf16 A-tile, then fp32 out-tile
    int tid = threadIdx.x;
    int wid = tid >> 6, lane = tid & 63;
    int c0 = blockIdx.x * CPB;

    // zero the A-tile (2048 uint4 / 512 threads)
    uint4 z4 = {0u, 0u, 0u, 0u};
    #pragma unroll
    for (int k = 0; k < 4; ++k) ((uint4*)s)[tid + 512 * k] = z4;
    __syncthreads();

#define FLUSH() *(uint32_t*)((char*)s + flushByte) = packrn(a0, a1)
#define PROC(mx, cf, u) do{                                                       \
        int fk_ = (int)(((unsigned)(mx)) >> 25);                                  \
        if (fk_ != fkPrev){                                                       \
            if (fkPrev >= 0) FLUSH();                                             \
            fkPrev = fk_;                                                         \
            flushByte = (fk_ << 8) + ((lane << 2) ^ ((fk_ << 1) & 0x70));         \
            a0 = 0.f; a1 = 0.f;                                                   \
        }                                                                         \
        a0 = fmaf(cf, bf2f((u) & 0xFFFFu), a0);                                   \
        a1 = fmaf(cf, bf2f((u) >> 16),     a1); }while(0)
#define XROW(mx) ((const uint32_t*)xbin)[((size_t)(((mx) & 0x1FFFF) << 6)) + lane]

    // ---- phase 1: 2 cols per wave, one contiguous edge range ----
    {
        int c = c0 + wid * 2;
        if (c < N){
            int cHi = c + 2; if (cHi > N) cHi = N;
            int e  = cs8[c * NREL];
            int eE = cs8[cHi * NREL];
            int fkPrev = -1;
            int flushByte = 0;
            float a0 = 0.f, a1 = 0.f;
            while (e < eE){
                int n = eE - e; if (n > 64) n = 64;
                int li = lane < n ? lane : n - 1;
                int2 mv = pkm[e + li];            // 64 metas, one coalesced load
                int j = 0;
                for (; j + 16 <= n; j += 16){     // full batches: no masking
                    int mxs[16]; float cfs[16]; uint32_t u[16];
                    #pragma unroll
                    for (int k = 0; k < 16; ++k){
                        mxs[k] = __builtin_amdgcn_readlane(mv.x, j + k);
                        cfs[k] = asf(__builtin_amdgcn_readlane(mv.y, j + k));
                    }
                    #pragma unroll
                    for (int k = 0; k < 16; ++k) u[k] = XROW(mxs[k]);
                    __builtin_amdgcn_sched_barrier(0);
                    #pragma unroll
                    for (int k = 0; k < 16; ++k) PROC(mxs[k], cfs[k], u[k]);
                }
                if (j < n){                        // single masked tail batch
                    int mxs[16]; float cfs[16]; uint32_t u[16];
                    #pragma unroll
                    for (int k = 0; k < 16; ++k){
                        int idx = j + k;
                        int live = idx < n;
                        idx = live ? idx : n - 1;           // clamp: duplicate last edge
                        mxs[k] = __builtin_amdgcn_readlane(mv.x, idx);
                        float cv = asf(__builtin_amdgcn_readlane(mv.y, idx));
                        cfs[k] = live ? cv : 0.f;           // masked slots contribute 0
                    }
                    #pragma unroll
                    for (int k = 0; k < 16; ++k) u[k] = XROW(mxs[k]);
                    __builtin_amdgcn_sched_barrier(0);
                    #pragma unroll
                    for (int k = 0; k < 16; ++k) PROC(mxs[k], cfs[k], u[k]);
                }
                e += n;
            }
            if (fkPrev >= 0) FLUSH();
        }
    }
#undef PROC
#undef FLUSH
#undef XROW
    __syncthreads();

    // ---- phase 2: wave nt=wid: one 16(rows) x 16(dims) tile, K=1024 ----
    int nt = wid;
    f32x4 acc = (f32x4){0,0,0,0};

    int al = lane & 15, ak2 = (lane >> 4) * 16;
    int swz = (al & 7) << 4;
    const char* rowA = (const char*)s + al * 2048;

    const short8* bbase = (const short8*)wpk + (size_t)wslot * 2048 + lane;

    #pragma unroll 4
    for (int ksg = 0; ksg < 32; ++ksg){
        int off = (ksg * 64 + ak2) ^ swz;
        short8 A = *(const short8*)(rowA + off);
        int t = ksg >> 2, ksl = ksg & 3;
        short8 B = (bbase + (size_t)t * 2048)[(nt * 4 + ksl) * 64];
        acc = __builtin_amdgcn_mfma_f32_16x16x32_bf16(A, B, acc, 0, 0, 0);
    }
    __syncthreads();   // all A-reads done; reuse s as fp32 out-tile

    // ---- stage C tile to LDS (bias + relu applied here) ----
    float* ot = (float*)s;   // [CPB][128]
    int crb = (lane >> 4) * 4, dcl = lane & 15;
    {
        int d = nt * 16 + dcl;
        float bv = bias[d];
        #pragma unroll
        for (int r = 0; r < 4; ++r){
            int mrow = crb + r;
            float v = acc[r] + bv;
            if (MODE == 0) v = fmaxf(v, 0.f);
            ot[mrow * DIM + d] = v;
        }
    }
    __syncthreads();

    // ---- coalesced output ----
    if (MODE == 0){
        if (tid < 256){
            int rowi = tid >> 4, seg = tid & 15;
            int c = c0 + rowi;
            if (c < N){
                const float* src = ot + rowi * DIM + seg * 8;
                uint4 vv;
                vv.x = packrn(src[0], src[1]);
                vv.y = packrn(src[2], src[3]);
                vv.z = packrn(src[4], src[5]);
                vv.w = packrn(src[6], src[7]);
                *(uint4*)(zb + ((size_t)c << 7) + seg * 8) = vv;
            }
        }
    } else {
        int rowi = tid >> 5, q = tid & 31;
        int c = c0 + rowi;
        if (c < N){
            int d0 = q * 4;
            size_t o = ((size_t)c << 7) + d0;
            ushort4 xv4 = *(const ushort4*)(xb2 + o);
            ushort4 zv4 = *(const ushort4*)(z1b2 + o);
            const float* src = ot + rowi * DIM + d0;
            f32x4 S, H;
            {
                float xv = bf2f(xv4.x), z1 = bf2f(zv4.x), v = src[0];
                S.x = (xv + z1 + v) * 0.25f; H.x = (z1 + v) * (1.0f / 3.0f);
            }
            {
                float xv = bf2f(xv4.y), z1 = bf2f(zv4.y), v = src[1];
                S.y = (xv + z1 + v) * 0.25f; H.y = (z1 + v) * (1.0f / 3.0f);
            }
            {
                float xv = bf2f(xv4.z), z1 = bf2f(zv4.z), v = src[2];
                S.z = (xv + z1 + v) * 0.25f; H.z = (z1 + v) * (1.0f / 3.0f);
            }
            {
                float xv = bf2f(xv4.w), z1 = bf2f(zv4.w), v = src[3];
                S.w = (xv + z1 + v) * 0.25f; H.w = (z1 + v) * (1.0f / 3.0f);
            }
            __builtin_nontemporal_store(S, (f32x4*)(outS + o));
            __builtin_nontemporal_store(H, (f32x4*)(outH + o));
        }
    }
}

extern "C" void kernel_launch(void* const* d_in, const int* in_sizes, int n_in,
                              void* d_out, int out_size, void* d_ws, size_t ws_size,
                              hipStream_t stream) {
    const float* x  = (const float*)d_in[0];
    const int*   ei = (const int*)d_in[1];
    const int*   et = (const int*)d_in[2];
    const float* ew = (const float*)d_in[3];
    const float* W1 = (const float*)d_in[4];
    const float* b1 = (const float*)d_in[5];
    const float* W2 = (const float*)d_in[6];
    const float* b2 = (const float*)d_in[7];

    int E = in_sizes[2];
    int N = in_sizes[0] / DIM;
    const int* row = ei;
    const int* col = ei + E;

    float* out = (float*)d_out;
    int ND  = N * DIM;
    int ND4 = ND / 4;
    float* zS = out;        // slot 0: z_star
    float* zH = out + ND;   // slot 1: z_sharp

    int M8   = N * NREL;
    int NBS8 = cdiv(M8, SCB);

    // ---- workspace carve (~70 MB) ----
    char* wsb = (char*)d_ws;
    size_t off = 0;
    auto take = [&](size_t bytes) -> char* {
        char* p = wsb + off;
        off = (off + bytes + 255) & ~(size_t)255;
        return p;
    };
    int*            cnt8     = (int*)           take((size_t)M8 * 4);
    int*            start8   = (int*)           take(((size_t)M8 + 1) * 4);
    int*            pos8     = (int*)           take((size_t)M8 * 4);
    int*            bsum     = (int*)           take(((size_t)NBS8 + 1) * 4);
    int2*           pkm      = (int2*)          take((size_t)E * 8);
    unsigned short* wpk      = (unsigned short*)take((size_t)16 * 2048 * 8 * 2);   // 512 KB
    unsigned short* xb       = (unsigned short*)take((size_t)ND * 2);
    unsigned short* z1b      = (unsigned short*)take((size_t)ND * 2);
    (void)n_in; (void)out_size; (void)ws_size;

    hipMemsetAsync(cnt8, 0, (size_t)M8 * 4, stream);

    int eb  = cdiv(E, 256);
    int nb4 = cdiv(ND4, 256);
    k_prep  <<<nb4 + eb + 128, 256, 0, stream>>>((const float4*)x, xb, ND4, col, et, E, cnt8, nb4, eb, W1, W2, wpk);
    k_scan1 <<<NBS8, 256, 0, stream>>>(cnt8, M8, bsum);
    k_scan3 <<<NBS8, 256, 0, stream>>>(cnt8, M8, bsum, NBS8, start8, pos8);
    k_place <<<eb, 256, 0, stream>>>(row, col, et, ew, start8, E, pos8, pkm);

    int fb = cdiv(N, CPB);
    // conv1: z1b = bf16(relu(agg(x) @ W1 + b1))
    k_fused<0><<<fb, 512, 0, stream>>>(xb, wpk, start8, pkm, b1, z1b, nullptr, nullptr, nullptr, nullptr, N, 0);
    // conv2: fused z_star/z_sharp from xb, z1b, agg(z1b) @ W2 + b2
    k_fused<1><<<fb, 512, 0, stream>>>(z1b, wpk, start8, pkm, b2, nullptr, xb, z1b, zS, zH, N, 8);
}